// Round 14
// baseline (5370.707 us; speedup 1.0000x reference)
//
#include <hip/hip_runtime.h>

#define NR 512
#define NI 128
#define B 32
#define T 1000
#define KC 256   // OpenBLAS level3 driver K-panel rebalancing: K=512 -> [0,256)+[256,512)
// Locked numeric model (verified PASS round 13):
//  - input GEMM: per element single ascending-i FMA chain.
//  - z @ w_rec_masked: two 256-wide ascending-k chains (panels), one rounded join add.
//    Binary z => only active rows; masked diag = exact +0 add in-chain.
//  - elementwise: separate rounded f32 ops ((f32(decay)*v) + i_t) - z.
// This round: SAME arithmetic, parallelized — panel chains s1,s2 are independent,
// so thread (u,h) computes panel h; 16-wide load groups; proj/EMA folded into the
// list-build window (3 barriers/step).

__device__ __forceinline__ float mul_nofma(float a, float b) {
    float r = a * b;
    asm volatile("" : "+v"(r));
    return r;
}

// ---------------- Kernel 1: i_in = inputs @ w_in -> voltages region of d_out
template <int ROWS>
__global__ __launch_bounds__(512) void k_in_gemm(const float* __restrict__ inputs,
                                                 const float* __restrict__ w_in,
                                                 float* __restrict__ i_in) {
    const int u = threadIdx.x;
    const int r0 = blockIdx.x * ROWS;
    float acc[ROWS];
#pragma unroll
    for (int r = 0; r < ROWS; ++r) acc[r] = 0.f;
    const float* __restrict__ inp = inputs + (long)r0 * NI;
#pragma unroll 4
    for (int i = 0; i < NI; ++i) {
        float w = w_in[i * NR + u];
#pragma unroll
        for (int r = 0; r < ROWS; ++r)
            acc[r] = __builtin_fmaf(inp[r * NI + i], w, acc[r]);   // ascending i, FMA
    }
#pragma unroll
    for (int r = 0; r < ROWS; ++r)
        i_in[(long)(r0 + r) * NR + u] = acc[r];
}

// ---------------- Kernel 2: per-batch LIF scan, panel-parallel (u, h) threads.
// 32 blocks x 1024 threads: tid = (h<<9)|u ; h=0 sums panel j<256, h=1 j>=256.
__global__ __launch_bounds__(1024) void k_scan(const float* __restrict__ w_rec,
                                               const float* __restrict__ w_out,
                                               const float* __restrict__ b_out,
                                               float* __restrict__ out) {
    const int b = blockIdx.x;
    const int tid = threadIdx.x;
    const int u = tid & (NR - 1);
    const int h = tid >> 9;
    const int wav = tid >> 6;          // 0..15 ; waves 0..7 carry the canonical z
    const int lane = tid & 63;

    float* __restrict__ volt_b = out + (long)b * (T * NR);                 // also i_in (in-place)
    float* __restrict__ spk_b  = out + (long)B * T * NR + (long)b * (T * NR);
    float* __restrict__ pred   = out + 2L * B * T * NR + (long)b * T;

    __shared__ __align__(16) int list[NR];
    __shared__ int wcnt[8];
    __shared__ float sh_s[2][NR];
    __shared__ double projp[8];

    float v = 0.f, z = 0.f;
    const float decay = 0.951229424500714f;   // f32 rounding of the python scalar
    const double wo = (double)w_out[u];
    const double bo = (double)b_out[0];
    double ema = 0.0;                          // thread 0's copy is canonical

    for (int t = 0; t < T; ++t) {
        float ii = volt_b[t * NR + u];         // issue early; used after the chain

        // ---- ballot (z == spikes[t-1]) + projection of z for pred[t-1]
        unsigned long long m = __ballot(z > 0.5f);
        double p = (double)z * wo;
#pragma unroll
        for (int o = 32; o > 0; o >>= 1) p += __shfl_xor(p, o, 64);
        if (wav < 8 && lane == 0) { wcnt[wav] = __popcll(m); projp[wav] = p; }
        __syncthreads();                       // A: wcnt + projp ready

        int cnt = 0, base = 0;
#pragma unroll
        for (int w2 = 0; w2 < 8; ++w2) {
            int c = wcnt[w2];
            if (w2 < (wav & 7)) base += c;
            cnt += c;
        }
        const int cnt_lo = wcnt[0] + wcnt[1] + wcnt[2] + wcnt[3];
        if (tid < NR && z > 0.5f) {
            int pos = base + __popcll(m & ((1ull << lane) - 1ull));
            list[pos] = u;                     // ascending u order
        }
        if (tid == 0 && t > 0) {               // EMA for t-1, overlapped with list build
            double pr = bo;
#pragma unroll
            for (int w2 = 0; w2 < 8; ++w2) pr += projp[w2];
            ema = 0.8 * ema + 0.2 * pr;
            pred[t - 1] = (float)ema;
        }
        __syncthreads();                       // B: list ready

        // ---- panel chain for this thread's half: bit-exact ascending order
        const int kb = h ? cnt_lo : 0;
        const int ke = h ? cnt : cnt_lo;
        float s = 0.f;
        for (int k = kb; k < ke; k += 16) {
            const int rem = ke - k;
            float wv[16];
#pragma unroll
            for (int q = 0; q < 16; ++q) {
                int j = list[(q < rem) ? (k + q) : kb];     // in-bounds dummy for pad
                j = __builtin_amdgcn_readfirstlane(j);
                float w = w_rec[j * NR + u];
                if (q >= rem || j == u) w = 0.f;            // pad & masked diag: exact +0
                wv[q] = w;
            }
#pragma unroll
            for (int q = 0; q < 16; ++q) s = __fadd_rn(s, wv[q]);
        }
        sh_s[h][u] = s;
        __syncthreads();                       // C: both partials ready

        // ---- join + LIF update (reference op order, no contraction)
        float rec = __fadd_rn(sh_s[0][u], sh_s[1][u]);
        float it = __fadd_rn(ii, rec);
        float m1 = mul_nofma(decay, v);
        float t2 = __fadd_rn(m1, it);
        float vn = __fsub_rn(t2, z);
        float zn = (vn > 1.0f) ? 1.0f : 0.0f;
        if (h == 0) {
            volt_b[t * NR + u] = vn;
            spk_b[t * NR + u]  = zn;
        }
        v = vn; z = zn;                        // identical in both halves (same inputs/ops)
    }

    // ---- final pred[T-1]
    {
        double p = (double)z * wo;
#pragma unroll
        for (int o = 32; o > 0; o >>= 1) p += __shfl_xor(p, o, 64);
        if (wav < 8 && lane == 0) projp[wav] = p;
        __syncthreads();
        if (tid == 0) {
            double pr = bo;
#pragma unroll
            for (int w2 = 0; w2 < 8; ++w2) pr += projp[w2];
            ema = 0.8 * ema + 0.2 * pr;
            pred[T - 1] = (float)ema;
        }
    }
}

extern "C" void kernel_launch(void* const* d_in, const int* in_sizes, int n_in,
                              void* d_out, int out_size, void* d_ws, size_t ws_size,
                              hipStream_t stream) {
    const float* inputs = (const float*)d_in[0];
    const float* w_in   = (const float*)d_in[1];
    const float* w_rec  = (const float*)d_in[2];
    const float* w_out  = (const float*)d_in[3];
    const float* b_out  = (const float*)d_in[4];
    float* out = (float*)d_out;

    k_in_gemm<16><<<dim3(B * T / 16), dim3(512), 0, stream>>>(inputs, w_in, out);
    k_scan<<<dim3(B), dim3(1024), 0, stream>>>(w_rec, w_out, b_out, out);
}